// Round 7
// baseline (302.168 us; speedup 1.0000x reference)
//
#include <hip/hip_runtime.h>

// B=4, C=512, L=2048, H=8, D=64. f32 inputs, f32 output.
// Universal fragment-packed layouts (r4): every MFMA operand load everywhere is
// one lane-contiguous 1KB read. r5: attn 64 i-rows/block. r6 (qkv 64x64 retile)
// FAILED neutral -> reverted; GEMMs back to r5-measured config.
// r7: *** attn TLP: 4-wave j-split (each wave 512 j), V loaded per-iteration
// (drops vn prefetch regs), __launch_bounds__(256,3) -> 3 waves/SIMD
// (r5 was VGPR=200 = 2/SIMD; pipe-work arithmetic shows 5x latency slack).
// Partials combine by plain addition (sum-normalized softmax) via 52KB LDS. ***

#define LDIM 2048
#define CDIM 512
#define BATCH 4

typedef __attribute__((ext_vector_type(8))) short s16x8;
typedef __attribute__((ext_vector_type(4))) float f32x4;
typedef __attribute__((ext_vector_type(4))) unsigned short u16x4;
typedef unsigned int u32;
typedef unsigned short u16;

__device__ __forceinline__ u16 f2b(float f) {
    unsigned u = __float_as_uint(f);
    u += 0x7fffu + ((u >> 16) & 1u);   // RNE
    return (u16)(u >> 16);
}
// pack two floats -> two bf16 (round-half-up) in one u32 (b in high half)
__device__ __forceinline__ u32 pk2(float a, float b) {
    u32 ua = __float_as_uint(a) + 0x8000u;
    u32 ub = __float_as_uint(b) + 0x8000u;
    return __builtin_amdgcn_perm(ub, ua, 0x07060302u);  // {ub.hi16, ua.hi16}
}

// ---------------- unified transpose + f32->bf16 convert -> packed chunks -------
// chunk(row,col): elem(rtile*16+mn, cstep*32+q*8+e) at ((rtile*16+cstep)*64+lane)*8+e
__global__ __launch_bounds__(256)
void transpA_k(const float* __restrict__ x, const float* __restrict__ wq,
               const float* __restrict__ wo, u16* __restrict__ XP,
               u16* __restrict__ WP, u16* __restrict__ WOP)
{
    const int r0 = blockIdx.x * 64;
    const int y  = blockIdx.y;
    const float* in; u16* out; int inLD, c0;
    if (y < 128) {
        const int b = y >> 5, ct = y & 31;
        in = x + (size_t)b * CDIM * LDIM; inLD = LDIM; c0 = ct * 64;
        out = XP + (size_t)b * LDIM * CDIM;
    } else if (y < 152) {
        in = wq; inLD = 1536; c0 = (y - 128) * 64; out = WP;
    } else {
        in = wo; inLD = 512;  c0 = (y - 152) * 64; out = WOP;
    }

    __shared__ __align__(16) u16 t[64][80];
    const int tt = threadIdx.x;
    const int lr = tt >> 4, lc = (tt & 15) * 4;
    #pragma unroll
    for (int i = 0; i < 4; ++i) {
        f32x4 v = *(const f32x4*)(in + (size_t)(r0 + lr + i * 16) * inLD + c0 + lc);
        #pragma unroll
        for (int j = 0; j < 4; ++j) t[lc + j][lr + i * 16] = f2b(v[j]);
    }
    __syncthreads();
    const int orow = tt >> 2, ocg = (tt & 3) * 16;
    s16x8 v0 = *(const s16x8*)&t[orow][ocg];
    s16x8 v1 = *(const s16x8*)&t[orow][ocg + 8];
    const int row   = c0 + orow;            // l (or f) index
    const int rtile = row >> 4, rr = row & 15;
    const int cstep = (r0 + ocg) >> 5;      // 32-col step within CDIM-like axis
    const int qb    = (ocg >> 3) & 3;       // 0 or 2
    u16* dst = out + ((size_t)(rtile * 16 + cstep) * 64 + qb * 16 + rr) * 8;
    *(s16x8*)dst = v0;                      // q = qb   half
    *(s16x8*)(dst + 128) = v1;              // q = qb+1 half
}

// ---------------- QKV GEMM (r5 config): packed-chunk loads -> QF/KF/VF --------
__global__ __launch_bounds__(256)
void qkvgemm_bf16(const u16* __restrict__ XP, const u16* __restrict__ WP,
                  u16* __restrict__ QF, u16* __restrict__ KF, u16* __restrict__ VF)
{
    const int f0 = blockIdx.x * 64;
    const int l0 = blockIdx.y * 128;
    const int b  = blockIdx.z;
    const u16* xTb = XP + (size_t)b * LDIM * CDIM;
    const int t = threadIdx.x, w = t >> 6, lane = t & 63;
    const int mn = lane & 15, q = lane >> 4;
    const bool vpart = (f0 >= 1024);

    const u16 *Abase, *Bbase;
    int mbase, nbase;
    if (!vpart) {
        mbase = f0 + (w >> 1) * 32; nbase = l0 + (w & 1) * 64;
        Abase = WP + (size_t)mbase * CDIM; Bbase = xTb + (size_t)nbase * CDIM;
    } else {
        mbase = l0 + w * 32; nbase = f0;
        Abase = xTb + (size_t)mbase * CDIM; Bbase = WP + (size_t)nbase * CDIM;
    }

    f32x4 acc[2][4] = {};
    #pragma unroll 2
    for (int c0 = 0; c0 < CDIM; c0 += 32) {
        s16x8 a[2], bf[4];
        #pragma unroll
        for (int mi = 0; mi < 2; ++mi)
            a[mi] = *(const s16x8*)(Abase + mi * 16 * CDIM + c0 * 16 + lane * 8);
        #pragma unroll
        for (int ni = 0; ni < 4; ++ni)
            bf[ni] = *(const s16x8*)(Bbase + ni * 16 * CDIM + c0 * 16 + lane * 8);
        #pragma unroll
        for (int mi = 0; mi < 2; ++mi)
            #pragma unroll
            for (int ni = 0; ni < 4; ++ni)
                acc[mi][ni] = __builtin_amdgcn_mfma_f32_16x16x32_bf16(a[mi], bf[ni], acc[mi][ni], 0, 0, 0);
    }

    if (!vpart) {
        const int part = f0 >> 9;
        const float sc2 = (part == 0) ? 0.18033688f : 1.0f;  // 0.125*log2(e)
        u16* Tout = (part == 0) ? QF : KF;
        #pragma unroll
        for (int mi = 0; mi < 2; ++mi) {
            const int fg0 = mbase + mi * 16;
            const int h = (fg0 >> 6) & 7;
            const int d0 = (fg0 & 63) + q * 4;          // 4-aligned d base
            const int kd = d0 >> 5, qq = (d0 >> 3) & 3, e0 = d0 & 7;
            u16* T = Tout + (size_t)(b * 8 + h) * LDIM * 64;
            #pragma unroll
            for (int ni = 0; ni < 4; ++ni) {
                const int lg = nbase + ni * 16 + mn;     // L index
                size_t addr;
                if (part == 0) {                         // QF[t16][kd][lane][8]
                    const int t16 = lg >> 4, mnq = lg & 15;
                    addr = (size_t)((t16 * 2 + kd) * 512 + (qq * 16 + mnq) * 8 + e0);
                } else {                                 // KF[j64][jt][kd][lane][8], kperm absorbed
                    const int j64 = lg >> 6, r6 = lg & 63;
                    const int jt  = ((r6 >> 2) & 1) * 2 + (r6 >> 5);
                    const int mnk = ((r6 >> 3) & 3) * 4 + (r6 & 3);
                    addr = (size_t)(((j64 * 4 + jt) * 2 + kd) * 512 + (qq * 16 + mnk) * 8 + e0);
                }
                u16x4 pk;
                #pragma unroll
                for (int r = 0; r < 4; ++r) pk[r] = f2b(acc[mi][ni][r] * sc2);
                *(u16x4*)(T + addr) = pk;
            }
        }
    } else {
        #pragma unroll
        for (int ni = 0; ni < 4; ++ni) {
            const int fg = nbase + ni * 16 + mn;
            const int h = (fg >> 6) & 7;
            const int d = fg & 63;
            const int dt = d >> 4, mnv = d & 15;
            u16* Vb = VF + (size_t)(b * 8 + h) * LDIM * 64;
            #pragma unroll
            for (int mi = 0; mi < 2; ++mi) {
                const int lg0 = mbase + mi * 16 + q * 4;    // 4-aligned j base
                const int j64 = lg0 >> 6, j6 = lg0 & 63;
                const int kj = j6 >> 5, qq = (j6 >> 3) & 3, e0 = j6 & 7;
                const size_t addr = (size_t)(((j64 * 2 + kj) * 4 + dt) * 512 + (qq * 16 + mnv) * 8 + e0);
                u16x4 pk;
                #pragma unroll
                for (int r = 0; r < 4; ++r) pk[r] = f2b(acc[mi][ni][r]);
                *(u16x4*)(Vb + addr) = pk;
            }
        }
    }
}

// ---------------- Flash attention: 64 i-rows, 4-wave j-split, 3 waves/SIMD ------
// grid (x=bh 32, y=32), 256 threads (4 waves). Wave wv owns j in [wv*512,(wv+1)*512).
// K register-prefetched 1 tile ahead; V loaded per-iteration (exp2 phase covers L2).
__global__ __launch_bounds__(256, 3)
void attn_k(const u16* __restrict__ QF, const u16* __restrict__ KF,
            const u16* __restrict__ VF, u16* __restrict__ aoP)
{
    const int bh = blockIdx.x;
    const int b = bh >> 3, h = bh & 7;
    const u16* Qh = QF + (size_t)bh * LDIM * 64;
    const u16* Kh = KF + (size_t)bh * LDIM * 64;
    const u16* Vh = VF + (size_t)bh * LDIM * 64;

    __shared__ __align__(16) float o_sh[3][64][68];   // waves 1..3 partials (+4 pad)
    __shared__ float lp_sh[3][64];

    const int tid = threadIdx.x;
    const int wv = tid >> 6;
    const int lane = tid & 63;
    const int mn = lane & 15, q = lane >> 4;
    const int ib64 = blockIdx.y;         // 64-row i-block
    const int TH = 8;                    // j-tiles per wave (of 32 total)
    const int tbase = wv * TH;

    s16x8 aq[4][2];
    #pragma unroll
    for (int ibt = 0; ibt < 4; ++ibt) {
        const int t16 = ib64 * 4 + ibt;
        #pragma unroll
        for (int kd = 0; kd < 2; ++kd)
            aq[ibt][kd] = *(const s16x8*)(Qh + (size_t)((t16 * 2 + kd) * 512) + lane * 8);
    }

    f32x4 o_acc[4][4] = {};
    float lp[4] = {0.f, 0.f, 0.f, 0.f};

    // preload this wave's tile-0 K fragments (coalesced)
    s16x8 kc[2][4];
    {
        const u16* Kt = Kh + (size_t)tbase * 4096;
        #pragma unroll
        for (int kd = 0; kd < 2; ++kd)
            #pragma unroll
            for (int jt = 0; jt < 4; ++jt)
                kc[kd][jt] = *(const s16x8*)(Kt + ((jt * 2 + kd) << 9) + (lane << 3));
    }

    #pragma unroll 2
    for (int jj = 0; jj < TH; ++jj) {
        const int tn = tbase + ((jj + 1) & (TH - 1));   // last iter wraps (L2-hot)
        const u16* Kt = Kh + (size_t)tn * 4096;
        const u16* Vt = Vh + (size_t)(tbase + jj) * 4096;   // CURRENT tile's V

        // issue next tile's K loads FIRST
        s16x8 kn[2][4];
        #pragma unroll
        for (int kd = 0; kd < 2; ++kd)
            #pragma unroll
            for (int jt = 0; jt < 4; ++jt)
                kn[kd][jt] = *(const s16x8*)(Kt + ((jt * 2 + kd) << 9) + (lane << 3));

        // S^T = K.Q^T on current K: 32 MFMA (4 ibt)
        f32x4 s[4][4] = {};
        #pragma unroll
        for (int kd = 0; kd < 2; ++kd)
            #pragma unroll
            for (int jt = 0; jt < 4; ++jt)
                #pragma unroll
                for (int ibt = 0; ibt < 4; ++ibt)
                    s[ibt][jt] = __builtin_amdgcn_mfma_f32_16x16x32_bf16(kc[kd][jt], aq[ibt][kd], s[ibt][jt], 0, 0, 0);

        // current tile's V loads: issued here, consumed after the exp2 phase
        s16x8 vc[2][4];
        #pragma unroll
        for (int kj = 0; kj < 2; ++kj)
            #pragma unroll
            for (int dt = 0; dt < 4; ++dt)
                vc[kj][dt] = *(const s16x8*)(Vt + ((kj * 4 + dt) << 9) + (lane << 3));

        // p = 2^s; build PV B-fragments fully in-register (lane-local j-slots).
        #pragma unroll
        for (int kj = 0; kj < 2; ++kj) {
            s16x8 ap[4];
            #pragma unroll
            for (int ibt = 0; ibt < 4; ++ibt) {
                float pa0 = __builtin_amdgcn_exp2f(s[ibt][kj][0]);
                float pa1 = __builtin_amdgcn_exp2f(s[ibt][kj][1]);
                float pa2 = __builtin_amdgcn_exp2f(s[ibt][kj][2]);
                float pa3 = __builtin_amdgcn_exp2f(s[ibt][kj][3]);
                float pb0 = __builtin_amdgcn_exp2f(s[ibt][kj + 2][0]);
                float pb1 = __builtin_amdgcn_exp2f(s[ibt][kj + 2][1]);
                float pb2 = __builtin_amdgcn_exp2f(s[ibt][kj + 2][2]);
                float pb3 = __builtin_amdgcn_exp2f(s[ibt][kj + 2][3]);
                lp[ibt] += ((pa0 + pa1) + (pa2 + pa3)) + ((pb0 + pb1) + (pb2 + pb3));
                union { s16x8 v; u32 w[4]; } u;
                u.w[0] = pk2(pa0, pa1);
                u.w[1] = pk2(pa2, pa3);
                u.w[2] = pk2(pb0, pb1);
                u.w[3] = pk2(pb2, pb3);
                ap[ibt] = u.v;
            }
            #pragma unroll
            for (int dt = 0; dt < 4; ++dt)
                #pragma unroll
                for (int ibt = 0; ibt < 4; ++ibt)
                    o_acc[ibt][dt] = __builtin_amdgcn_mfma_f32_16x16x32_bf16(vc[kj][dt], ap[ibt], o_acc[ibt][dt], 0, 0, 0);
        }

        // rotate prefetched K registers
        #pragma unroll
        for (int kd = 0; kd < 2; ++kd)
            #pragma unroll
            for (int jt = 0; jt < 4; ++jt)
                kc[kd][jt] = kn[kd][jt];
    }

    #pragma unroll
    for (int ibt = 0; ibt < 4; ++ibt) {
        lp[ibt] += __shfl_xor(lp[ibt], 16);
        lp[ibt] += __shfl_xor(lp[ibt], 32);
    }

    // combine the four waves' j-partials: plain addition (sum-normalized softmax)
    if (wv != 0) {
        #pragma unroll
        for (int ibt = 0; ibt < 4; ++ibt) {
            #pragma unroll
            for (int dt = 0; dt < 4; ++dt)
                *(f32x4*)&o_sh[wv - 1][ibt * 16 + mn][dt * 16 + q * 4] = o_acc[ibt][dt];
            if (q == 0) lp_sh[wv - 1][ibt * 16 + mn] = lp[ibt];
        }
    }
    __syncthreads();
    if (wv == 0) {
        u16* Ab = aoP + (size_t)b * LDIM * 512;
        #pragma unroll
        for (int ibt = 0; ibt < 4; ++ibt) {
            const int row = ibt * 16 + mn;
            const float lptot = lp[ibt] + lp_sh[0][row] + lp_sh[1][row] + lp_sh[2][row];
            const float rinv = 1.0f / lptot;
            const int ltile = ib64 * 4 + ibt;
            #pragma unroll
            for (int dt = 0; dt < 4; ++dt) {
                f32x4 o0 = *(const f32x4*)&o_sh[0][row][dt * 16 + q * 4];
                f32x4 o1 = *(const f32x4*)&o_sh[1][row][dt * 16 + q * 4];
                f32x4 o2 = *(const f32x4*)&o_sh[2][row][dt * 16 + q * 4];
                u16x4 pk;
                #pragma unroll
                for (int r = 0; r < 4; ++r)
                    pk[r] = f2b((o_acc[ibt][dt][r] + o0[r] + o1[r] + o2[r]) * rinv);
                // packed-chunk store: col = h*64 + dt*16 + q*4 + r
                const int cstep = h * 2 + (dt >> 1);
                const int lanep = ((dt & 1) * 2 + (q >> 1)) * 16 + mn;
                u16* dst = Ab + ((size_t)(ltile * 16 + cstep) * 64 + lanep) * 8 + (q & 1) * 4;
                *(u16x4*)dst = pk;
            }
        }
    }
}

// ---------------- Output GEMM (r5 config): packed-chunk loads ----------------
__global__ __launch_bounds__(256)
void outgemm_d(const u16* __restrict__ aoP, const u16* __restrict__ WOP,
               const float* __restrict__ bias, float* __restrict__ Y)
{
    const int f0 = blockIdx.x * 64;
    const int l0 = blockIdx.y * 128;
    const int b  = blockIdx.z;
    const int t = threadIdx.x, w = t >> 6, lane = t & 63;
    const int mn = lane & 15, q = lane >> 4;
    const int mbase = f0 + (w >> 1) * 32;
    const int nbase = l0 + (w & 1) * 64;
    const u16* Abase = WOP + (size_t)mbase * CDIM;
    const u16* Bbase = aoP + ((size_t)b * LDIM + nbase) * CDIM;
    float* Yb = Y + (size_t)b * CDIM * LDIM;

    f32x4 acc[2][4] = {};
    #pragma unroll 2
    for (int c0 = 0; c0 < CDIM; c0 += 32) {
        s16x8 a[2], bf[4];
        #pragma unroll
        for (int mi = 0; mi < 2; ++mi)
            a[mi] = *(const s16x8*)(Abase + mi * 16 * CDIM + c0 * 16 + lane * 8);
        #pragma unroll
        for (int ni = 0; ni < 4; ++ni)
            bf[ni] = *(const s16x8*)(Bbase + ni * 16 * CDIM + c0 * 16 + lane * 8);
        #pragma unroll
        for (int mi = 0; mi < 2; ++mi)
            #pragma unroll
            for (int ni = 0; ni < 4; ++ni)
                acc[mi][ni] = __builtin_amdgcn_mfma_f32_16x16x32_bf16(a[mi], bf[ni], acc[mi][ni], 0, 0, 0);
    }
    #pragma unroll
    for (int mi = 0; mi < 2; ++mi)
        #pragma unroll
        for (int r = 0; r < 4; ++r) {
            const int f = mbase + mi * 16 + q * 4 + r;
            const float bs = bias[f];
            #pragma unroll
            for (int ni = 0; ni < 4; ++ni)
                Yb[(size_t)f * LDIM + nbase + ni * 16 + mn] = acc[mi][ni][r] + bs;
        }
}

extern "C" void kernel_launch(void* const* d_in, const int* in_sizes, int n_in,
                              void* d_out, int out_size, void* d_ws, size_t ws_size,
                              hipStream_t stream) {
    const float *x = nullptr, *w_qkv = nullptr, *w_out = nullptr, *b_out = nullptr;
    for (int i = 0; i < n_in; ++i) {
        switch (in_sizes[i]) {
            case 4 * 512 * 2048: x     = (const float*)d_in[i]; break;
            case 512 * 1536:     w_qkv = (const float*)d_in[i]; break;
            case 512 * 512:      w_out = (const float*)d_in[i]; break;
            case 512:            b_out = (const float*)d_in[i]; break;
        }
    }
    float* out = (float*)d_out;                 // [4][512][2048] f32

    const size_t SLAB = (size_t)BATCH * LDIM * 512;      // 4194304 elems
    u16* WOP = (u16*)d_ws;                               // [512 rows][512] packed
    u16* XP  = WOP + (size_t)512 * 512;                  // [4][2048 rows][512] packed
    u16* WP  = XP + SLAB;                                // [1536 rows][512] packed
    u16* QF  = WP + (size_t)1536 * 512;                  // [32][2048*64] attn-packed
    u16* KF  = QF + SLAB;                                // [32][2048*64] attn-packed
    u16* VF  = KF + SLAB;                                // [32][2048*64] attn-packed
    u16* aoP = VF + SLAB;                                // [4][2048 rows][512] packed

    transpA_k<<<dim3(8, 160), 256, 0, stream>>>(x, w_qkv, w_out, XP, WP, WOP);
    qkvgemm_bf16<<<dim3(24, 16, BATCH), 256, 0, stream>>>(XP, WP, QF, KF, VF);
    attn_k<<<dim3(32, 32), 256, 0, stream>>>(QF, KF, VF, aoP);
    outgemm_d<<<dim3(8, 16, BATCH), 256, 0, stream>>>(aoP, WOP, b_out, out);
}

// Round 8
// 178.942 us; speedup vs baseline: 1.6886x; 1.6886x over previous
//
#include <hip/hip_runtime.h>

// B=4, C=512, L=2048, H=8, D=64. f32 inputs, f32 output.
// Universal fragment-packed layouts (r4): every MFMA operand load everywhere is
// one lane-contiguous 1KB read. r5: attn 64 i-rows/block (67us). r6 qkv-retile
// neutral -> reverted. r7 FAILED: __launch_bounds__(256,3) forced VGPR=84 ->
// massive scratch spill (FETCH 293MB, WRITE 522MB). r8: *** same 4-wave j-split
// attn (V per-iteration, no vn prefetch regs => ~168 VGPR natural) with PLAIN
// __launch_bounds__(256): if VGPR<=170 we get 3 blocks/CU = 3 waves/SIMD
// (LDS 52.3KB*3=157<=160KB); if not, perf degrades gracefully to r5 level. ***

#define LDIM 2048
#define CDIM 512
#define BATCH 4

typedef __attribute__((ext_vector_type(8))) short s16x8;
typedef __attribute__((ext_vector_type(4))) float f32x4;
typedef __attribute__((ext_vector_type(4))) unsigned short u16x4;
typedef unsigned int u32;
typedef unsigned short u16;

__device__ __forceinline__ u16 f2b(float f) {
    unsigned u = __float_as_uint(f);
    u += 0x7fffu + ((u >> 16) & 1u);   // RNE
    return (u16)(u >> 16);
}
// pack two floats -> two bf16 (round-half-up) in one u32 (b in high half)
__device__ __forceinline__ u32 pk2(float a, float b) {
    u32 ua = __float_as_uint(a) + 0x8000u;
    u32 ub = __float_as_uint(b) + 0x8000u;
    return __builtin_amdgcn_perm(ub, ua, 0x07060302u);  // {ub.hi16, ua.hi16}
}

// ---------------- unified transpose + f32->bf16 convert -> packed chunks -------
// chunk(row,col): elem(rtile*16+mn, cstep*32+q*8+e) at ((rtile*16+cstep)*64+lane)*8+e
__global__ __launch_bounds__(256)
void transpA_k(const float* __restrict__ x, const float* __restrict__ wq,
               const float* __restrict__ wo, u16* __restrict__ XP,
               u16* __restrict__ WP, u16* __restrict__ WOP)
{
    const int r0 = blockIdx.x * 64;
    const int y  = blockIdx.y;
    const float* in; u16* out; int inLD, c0;
    if (y < 128) {
        const int b = y >> 5, ct = y & 31;
        in = x + (size_t)b * CDIM * LDIM; inLD = LDIM; c0 = ct * 64;
        out = XP + (size_t)b * LDIM * CDIM;
    } else if (y < 152) {
        in = wq; inLD = 1536; c0 = (y - 128) * 64; out = WP;
    } else {
        in = wo; inLD = 512;  c0 = (y - 152) * 64; out = WOP;
    }

    __shared__ __align__(16) u16 t[64][80];
    const int tt = threadIdx.x;
    const int lr = tt >> 4, lc = (tt & 15) * 4;
    #pragma unroll
    for (int i = 0; i < 4; ++i) {
        f32x4 v = *(const f32x4*)(in + (size_t)(r0 + lr + i * 16) * inLD + c0 + lc);
        #pragma unroll
        for (int j = 0; j < 4; ++j) t[lc + j][lr + i * 16] = f2b(v[j]);
    }
    __syncthreads();
    const int orow = tt >> 2, ocg = (tt & 3) * 16;
    s16x8 v0 = *(const s16x8*)&t[orow][ocg];
    s16x8 v1 = *(const s16x8*)&t[orow][ocg + 8];
    const int row   = c0 + orow;            // l (or f) index
    const int rtile = row >> 4, rr = row & 15;
    const int cstep = (r0 + ocg) >> 5;      // 32-col step within CDIM-like axis
    const int qb    = (ocg >> 3) & 3;       // 0 or 2
    u16* dst = out + ((size_t)(rtile * 16 + cstep) * 64 + qb * 16 + rr) * 8;
    *(s16x8*)dst = v0;                      // q = qb   half
    *(s16x8*)(dst + 128) = v1;              // q = qb+1 half
}

// ---------------- QKV GEMM (r5 config): packed-chunk loads -> QF/KF/VF --------
__global__ __launch_bounds__(256)
void qkvgemm_bf16(const u16* __restrict__ XP, const u16* __restrict__ WP,
                  u16* __restrict__ QF, u16* __restrict__ KF, u16* __restrict__ VF)
{
    const int f0 = blockIdx.x * 64;
    const int l0 = blockIdx.y * 128;
    const int b  = blockIdx.z;
    const u16* xTb = XP + (size_t)b * LDIM * CDIM;
    const int t = threadIdx.x, w = t >> 6, lane = t & 63;
    const int mn = lane & 15, q = lane >> 4;
    const bool vpart = (f0 >= 1024);

    const u16 *Abase, *Bbase;
    int mbase, nbase;
    if (!vpart) {
        mbase = f0 + (w >> 1) * 32; nbase = l0 + (w & 1) * 64;
        Abase = WP + (size_t)mbase * CDIM; Bbase = xTb + (size_t)nbase * CDIM;
    } else {
        mbase = l0 + w * 32; nbase = f0;
        Abase = xTb + (size_t)mbase * CDIM; Bbase = WP + (size_t)nbase * CDIM;
    }

    f32x4 acc[2][4] = {};
    #pragma unroll 2
    for (int c0 = 0; c0 < CDIM; c0 += 32) {
        s16x8 a[2], bf[4];
        #pragma unroll
        for (int mi = 0; mi < 2; ++mi)
            a[mi] = *(const s16x8*)(Abase + mi * 16 * CDIM + c0 * 16 + lane * 8);
        #pragma unroll
        for (int ni = 0; ni < 4; ++ni)
            bf[ni] = *(const s16x8*)(Bbase + ni * 16 * CDIM + c0 * 16 + lane * 8);
        #pragma unroll
        for (int mi = 0; mi < 2; ++mi)
            #pragma unroll
            for (int ni = 0; ni < 4; ++ni)
                acc[mi][ni] = __builtin_amdgcn_mfma_f32_16x16x32_bf16(a[mi], bf[ni], acc[mi][ni], 0, 0, 0);
    }

    if (!vpart) {
        const int part = f0 >> 9;
        const float sc2 = (part == 0) ? 0.18033688f : 1.0f;  // 0.125*log2(e)
        u16* Tout = (part == 0) ? QF : KF;
        #pragma unroll
        for (int mi = 0; mi < 2; ++mi) {
            const int fg0 = mbase + mi * 16;
            const int h = (fg0 >> 6) & 7;
            const int d0 = (fg0 & 63) + q * 4;          // 4-aligned d base
            const int kd = d0 >> 5, qq = (d0 >> 3) & 3, e0 = d0 & 7;
            u16* T = Tout + (size_t)(b * 8 + h) * LDIM * 64;
            #pragma unroll
            for (int ni = 0; ni < 4; ++ni) {
                const int lg = nbase + ni * 16 + mn;     // L index
                size_t addr;
                if (part == 0) {                         // QF[t16][kd][lane][8]
                    const int t16 = lg >> 4, mnq = lg & 15;
                    addr = (size_t)((t16 * 2 + kd) * 512 + (qq * 16 + mnq) * 8 + e0);
                } else {                                 // KF[j64][jt][kd][lane][8], kperm absorbed
                    const int j64 = lg >> 6, r6 = lg & 63;
                    const int jt  = ((r6 >> 2) & 1) * 2 + (r6 >> 5);
                    const int mnk = ((r6 >> 3) & 3) * 4 + (r6 & 3);
                    addr = (size_t)(((j64 * 4 + jt) * 2 + kd) * 512 + (qq * 16 + mnk) * 8 + e0);
                }
                u16x4 pk;
                #pragma unroll
                for (int r = 0; r < 4; ++r) pk[r] = f2b(acc[mi][ni][r] * sc2);
                *(u16x4*)(T + addr) = pk;
            }
        }
    } else {
        #pragma unroll
        for (int ni = 0; ni < 4; ++ni) {
            const int fg = nbase + ni * 16 + mn;
            const int h = (fg >> 6) & 7;
            const int d = fg & 63;
            const int dt = d >> 4, mnv = d & 15;
            u16* Vb = VF + (size_t)(b * 8 + h) * LDIM * 64;
            #pragma unroll
            for (int mi = 0; mi < 2; ++mi) {
                const int lg0 = mbase + mi * 16 + q * 4;    // 4-aligned j base
                const int j64 = lg0 >> 6, j6 = lg0 & 63;
                const int kj = j6 >> 5, qq = (j6 >> 3) & 3, e0 = j6 & 7;
                const size_t addr = (size_t)(((j64 * 2 + kj) * 4 + dt) * 512 + (qq * 16 + mnv) * 8 + e0);
                u16x4 pk;
                #pragma unroll
                for (int r = 0; r < 4; ++r) pk[r] = f2b(acc[mi][ni][r]);
                *(u16x4*)(Vb + addr) = pk;
            }
        }
    }
}

// ---------------- Flash attention: 64 i-rows, 4-wave j-split ------
// grid (x=bh 32, y=32), 256 threads (4 waves). Wave wv owns j in [wv*512,(wv+1)*512).
// K register-prefetched 1 tile ahead; V loaded per-iteration (exp2 phase covers L2).
// PLAIN launch_bounds: natural VGPR (~168). NO min-waves forcing (r7 lesson).
__global__ __launch_bounds__(256)
void attn_k(const u16* __restrict__ QF, const u16* __restrict__ KF,
            const u16* __restrict__ VF, u16* __restrict__ aoP)
{
    const int bh = blockIdx.x;
    const int b = bh >> 3, h = bh & 7;
    const u16* Qh = QF + (size_t)bh * LDIM * 64;
    const u16* Kh = KF + (size_t)bh * LDIM * 64;
    const u16* Vh = VF + (size_t)bh * LDIM * 64;

    __shared__ __align__(16) float o_sh[3][64][68];   // waves 1..3 partials (+4 pad)
    __shared__ float lp_sh[3][64];

    const int tid = threadIdx.x;
    const int wv = tid >> 6;
    const int lane = tid & 63;
    const int mn = lane & 15, q = lane >> 4;
    const int ib64 = blockIdx.y;         // 64-row i-block
    const int TH = 8;                    // j-tiles per wave (of 32 total)
    const int tbase = wv * TH;

    s16x8 aq[4][2];
    #pragma unroll
    for (int ibt = 0; ibt < 4; ++ibt) {
        const int t16 = ib64 * 4 + ibt;
        #pragma unroll
        for (int kd = 0; kd < 2; ++kd)
            aq[ibt][kd] = *(const s16x8*)(Qh + (size_t)((t16 * 2 + kd) * 512) + lane * 8);
    }

    f32x4 o_acc[4][4] = {};
    float lp[4] = {0.f, 0.f, 0.f, 0.f};

    // preload this wave's tile-0 K fragments (coalesced)
    s16x8 kc[2][4];
    {
        const u16* Kt = Kh + (size_t)tbase * 4096;
        #pragma unroll
        for (int kd = 0; kd < 2; ++kd)
            #pragma unroll
            for (int jt = 0; jt < 4; ++jt)
                kc[kd][jt] = *(const s16x8*)(Kt + ((jt * 2 + kd) << 9) + (lane << 3));
    }

    #pragma unroll 2
    for (int jj = 0; jj < TH; ++jj) {
        const int tn = tbase + ((jj + 1) & (TH - 1));   // last iter wraps (L2-hot)
        const u16* Kt = Kh + (size_t)tn * 4096;
        const u16* Vt = Vh + (size_t)(tbase + jj) * 4096;   // CURRENT tile's V

        // issue next tile's K loads FIRST
        s16x8 kn[2][4];
        #pragma unroll
        for (int kd = 0; kd < 2; ++kd)
            #pragma unroll
            for (int jt = 0; jt < 4; ++jt)
                kn[kd][jt] = *(const s16x8*)(Kt + ((jt * 2 + kd) << 9) + (lane << 3));

        // S^T = K.Q^T on current K: 32 MFMA (4 ibt)
        f32x4 s[4][4] = {};
        #pragma unroll
        for (int kd = 0; kd < 2; ++kd)
            #pragma unroll
            for (int jt = 0; jt < 4; ++jt)
                #pragma unroll
                for (int ibt = 0; ibt < 4; ++ibt)
                    s[ibt][jt] = __builtin_amdgcn_mfma_f32_16x16x32_bf16(kc[kd][jt], aq[ibt][kd], s[ibt][jt], 0, 0, 0);

        // current tile's V loads: issued here, consumed after the exp2 phase
        s16x8 vc[2][4];
        #pragma unroll
        for (int kj = 0; kj < 2; ++kj)
            #pragma unroll
            for (int dt = 0; dt < 4; ++dt)
                vc[kj][dt] = *(const s16x8*)(Vt + ((kj * 4 + dt) << 9) + (lane << 3));

        // p = 2^s; build PV B-fragments fully in-register (lane-local j-slots).
        #pragma unroll
        for (int kj = 0; kj < 2; ++kj) {
            s16x8 ap[4];
            #pragma unroll
            for (int ibt = 0; ibt < 4; ++ibt) {
                float pa0 = __builtin_amdgcn_exp2f(s[ibt][kj][0]);
                float pa1 = __builtin_amdgcn_exp2f(s[ibt][kj][1]);
                float pa2 = __builtin_amdgcn_exp2f(s[ibt][kj][2]);
                float pa3 = __builtin_amdgcn_exp2f(s[ibt][kj][3]);
                float pb0 = __builtin_amdgcn_exp2f(s[ibt][kj + 2][0]);
                float pb1 = __builtin_amdgcn_exp2f(s[ibt][kj + 2][1]);
                float pb2 = __builtin_amdgcn_exp2f(s[ibt][kj + 2][2]);
                float pb3 = __builtin_amdgcn_exp2f(s[ibt][kj + 2][3]);
                lp[ibt] += ((pa0 + pa1) + (pa2 + pa3)) + ((pb0 + pb1) + (pb2 + pb3));
                union { s16x8 v; u32 w[4]; } u;
                u.w[0] = pk2(pa0, pa1);
                u.w[1] = pk2(pa2, pa3);
                u.w[2] = pk2(pb0, pb1);
                u.w[3] = pk2(pb2, pb3);
                ap[ibt] = u.v;
            }
            #pragma unroll
            for (int dt = 0; dt < 4; ++dt)
                #pragma unroll
                for (int ibt = 0; ibt < 4; ++ibt)
                    o_acc[ibt][dt] = __builtin_amdgcn_mfma_f32_16x16x32_bf16(vc[kj][dt], ap[ibt], o_acc[ibt][dt], 0, 0, 0);
        }

        // rotate prefetched K registers
        #pragma unroll
        for (int kd = 0; kd < 2; ++kd)
            #pragma unroll
            for (int jt = 0; jt < 4; ++jt)
                kc[kd][jt] = kn[kd][jt];
    }

    #pragma unroll
    for (int ibt = 0; ibt < 4; ++ibt) {
        lp[ibt] += __shfl_xor(lp[ibt], 16);
        lp[ibt] += __shfl_xor(lp[ibt], 32);
    }

    // combine the four waves' j-partials: plain addition (sum-normalized softmax)
    if (wv != 0) {
        #pragma unroll
        for (int ibt = 0; ibt < 4; ++ibt) {
            #pragma unroll
            for (int dt = 0; dt < 4; ++dt)
                *(f32x4*)&o_sh[wv - 1][ibt * 16 + mn][dt * 16 + q * 4] = o_acc[ibt][dt];
            if (q == 0) lp_sh[wv - 1][ibt * 16 + mn] = lp[ibt];
        }
    }
    __syncthreads();
    if (wv == 0) {
        u16* Ab = aoP + (size_t)b * LDIM * 512;
        #pragma unroll
        for (int ibt = 0; ibt < 4; ++ibt) {
            const int row = ibt * 16 + mn;
            const float lptot = lp[ibt] + lp_sh[0][row] + lp_sh[1][row] + lp_sh[2][row];
            const float rinv = 1.0f / lptot;
            const int ltile = ib64 * 4 + ibt;
            #pragma unroll
            for (int dt = 0; dt < 4; ++dt) {
                f32x4 o0 = *(const f32x4*)&o_sh[0][row][dt * 16 + q * 4];
                f32x4 o1 = *(const f32x4*)&o_sh[1][row][dt * 16 + q * 4];
                f32x4 o2 = *(const f32x4*)&o_sh[2][row][dt * 16 + q * 4];
                u16x4 pk;
                #pragma unroll
                for (int r = 0; r < 4; ++r)
                    pk[r] = f2b((o_acc[ibt][dt][r] + o0[r] + o1[r] + o2[r]) * rinv);
                // packed-chunk store: col = h*64 + dt*16 + q*4 + r
                const int cstep = h * 2 + (dt >> 1);
                const int lanep = ((dt & 1) * 2 + (q >> 1)) * 16 + mn;
                u16* dst = Ab + ((size_t)(ltile * 16 + cstep) * 64 + lanep) * 8 + (q & 1) * 4;
                *(u16x4*)dst = pk;
            }
        }
    }
}

// ---------------- Output GEMM (r5 config): packed-chunk loads ----------------
__global__ __launch_bounds__(256)
void outgemm_d(const u16* __restrict__ aoP, const u16* __restrict__ WOP,
               const float* __restrict__ bias, float* __restrict__ Y)
{
    const int f0 = blockIdx.x * 64;
    const int l0 = blockIdx.y * 128;
    const int b  = blockIdx.z;
    const int t = threadIdx.x, w = t >> 6, lane = t & 63;
    const int mn = lane & 15, q = lane >> 4;
    const int mbase = f0 + (w >> 1) * 32;
    const int nbase = l0 + (w & 1) * 64;
    const u16* Abase = WOP + (size_t)mbase * CDIM;
    const u16* Bbase = aoP + ((size_t)b * LDIM + nbase) * CDIM;
    float* Yb = Y + (size_t)b * CDIM * LDIM;

    f32x4 acc[2][4] = {};
    #pragma unroll 2
    for (int c0 = 0; c0 < CDIM; c0 += 32) {
        s16x8 a[2], bf[4];
        #pragma unroll
        for (int mi = 0; mi < 2; ++mi)
            a[mi] = *(const s16x8*)(Abase + mi * 16 * CDIM + c0 * 16 + lane * 8);
        #pragma unroll
        for (int ni = 0; ni < 4; ++ni)
            bf[ni] = *(const s16x8*)(Bbase + ni * 16 * CDIM + c0 * 16 + lane * 8);
        #pragma unroll
        for (int mi = 0; mi < 2; ++mi)
            #pragma unroll
            for (int ni = 0; ni < 4; ++ni)
                acc[mi][ni] = __builtin_amdgcn_mfma_f32_16x16x32_bf16(a[mi], bf[ni], acc[mi][ni], 0, 0, 0);
    }
    #pragma unroll
    for (int mi = 0; mi < 2; ++mi)
        #pragma unroll
        for (int r = 0; r < 4; ++r) {
            const int f = mbase + mi * 16 + q * 4 + r;
            const float bs = bias[f];
            #pragma unroll
            for (int ni = 0; ni < 4; ++ni)
                Yb[(size_t)f * LDIM + nbase + ni * 16 + mn] = acc[mi][ni][r] + bs;
        }
}

extern "C" void kernel_launch(void* const* d_in, const int* in_sizes, int n_in,
                              void* d_out, int out_size, void* d_ws, size_t ws_size,
                              hipStream_t stream) {
    const float *x = nullptr, *w_qkv = nullptr, *w_out = nullptr, *b_out = nullptr;
    for (int i = 0; i < n_in; ++i) {
        switch (in_sizes[i]) {
            case 4 * 512 * 2048: x     = (const float*)d_in[i]; break;
            case 512 * 1536:     w_qkv = (const float*)d_in[i]; break;
            case 512 * 512:      w_out = (const float*)d_in[i]; break;
            case 512:            b_out = (const float*)d_in[i]; break;
        }
    }
    float* out = (float*)d_out;                 // [4][512][2048] f32

    const size_t SLAB = (size_t)BATCH * LDIM * 512;      // 4194304 elems
    u16* WOP = (u16*)d_ws;                               // [512 rows][512] packed
    u16* XP  = WOP + (size_t)512 * 512;                  // [4][2048 rows][512] packed
    u16* WP  = XP + SLAB;                                // [1536 rows][512] packed
    u16* QF  = WP + (size_t)1536 * 512;                  // [32][2048*64] attn-packed
    u16* KF  = QF + SLAB;                                // [32][2048*64] attn-packed
    u16* VF  = KF + SLAB;                                // [32][2048*64] attn-packed
    u16* aoP = VF + SLAB;                                // [4][2048 rows][512] packed

    transpA_k<<<dim3(8, 160), 256, 0, stream>>>(x, w_qkv, w_out, XP, WP, WOP);
    qkvgemm_bf16<<<dim3(24, 16, BATCH), 256, 0, stream>>>(XP, WP, QF, KF, VF);
    attn_k<<<dim3(32, 32), 256, 0, stream>>>(QF, KF, VF, aoP);
    outgemm_d<<<dim3(8, 16, BATCH), 256, 0, stream>>>(aoP, WOP, b_out, out);
}

// Round 9
// 175.890 us; speedup vs baseline: 1.7179x; 1.0174x over previous
//
#include <hip/hip_runtime.h>

// B=4, C=512, L=2048, H=8, D=64. f32 inputs, f32 output.
// Universal fragment-packed layouts (r4). r5: attn 64 i-rows (67.2us). r7 forced
// launch_bounds FAILED (spill). r8: 4-wave j-split = identical 67.2us at VGPR=204
// -> TLP is walled at 2 waves/SIMD; the floor is the serial per-iteration chain
// QK(310cy) -> exp/pack(470cy) -> PV(310cy).
// r9: *** SOFTWARE PIPELINE inside attn: keep P(jj) packed in regs (ap[2][4]);
// body computes QK(jj+1) then interleaves exp/pack(jj+1) [VALU] with PV(jj)
// [MFMA pipe] -- independent tiles, so the 470cy VALU block hides under PV.
// Single-buffered K (reload right after QK reads it) and V (reload right after
// PV reads it) cap persistent VGPR at ~196. NO launch-bounds forcing. ***

#define LDIM 2048
#define CDIM 512
#define BATCH 4

typedef __attribute__((ext_vector_type(8))) short s16x8;
typedef __attribute__((ext_vector_type(4))) float f32x4;
typedef __attribute__((ext_vector_type(4))) unsigned short u16x4;
typedef unsigned int u32;
typedef unsigned short u16;

__device__ __forceinline__ u16 f2b(float f) {
    unsigned u = __float_as_uint(f);
    u += 0x7fffu + ((u >> 16) & 1u);   // RNE
    return (u16)(u >> 16);
}
// pack two floats -> two bf16 (round-half-up) in one u32 (b in high half)
__device__ __forceinline__ u32 pk2(float a, float b) {
    u32 ua = __float_as_uint(a) + 0x8000u;
    u32 ub = __float_as_uint(b) + 0x8000u;
    return __builtin_amdgcn_perm(ub, ua, 0x07060302u);  // {ub.hi16, ua.hi16}
}

// ---------------- unified transpose + f32->bf16 convert -> packed chunks -------
// chunk(row,col): elem(rtile*16+mn, cstep*32+q*8+e) at ((rtile*16+cstep)*64+lane)*8+e
__global__ __launch_bounds__(256)
void transpA_k(const float* __restrict__ x, const float* __restrict__ wq,
               const float* __restrict__ wo, u16* __restrict__ XP,
               u16* __restrict__ WP, u16* __restrict__ WOP)
{
    const int r0 = blockIdx.x * 64;
    const int y  = blockIdx.y;
    const float* in; u16* out; int inLD, c0;
    if (y < 128) {
        const int b = y >> 5, ct = y & 31;
        in = x + (size_t)b * CDIM * LDIM; inLD = LDIM; c0 = ct * 64;
        out = XP + (size_t)b * LDIM * CDIM;
    } else if (y < 152) {
        in = wq; inLD = 1536; c0 = (y - 128) * 64; out = WP;
    } else {
        in = wo; inLD = 512;  c0 = (y - 152) * 64; out = WOP;
    }

    __shared__ __align__(16) u16 t[64][80];
    const int tt = threadIdx.x;
    const int lr = tt >> 4, lc = (tt & 15) * 4;
    #pragma unroll
    for (int i = 0; i < 4; ++i) {
        f32x4 v = *(const f32x4*)(in + (size_t)(r0 + lr + i * 16) * inLD + c0 + lc);
        #pragma unroll
        for (int j = 0; j < 4; ++j) t[lc + j][lr + i * 16] = f2b(v[j]);
    }
    __syncthreads();
    const int orow = tt >> 2, ocg = (tt & 3) * 16;
    s16x8 v0 = *(const s16x8*)&t[orow][ocg];
    s16x8 v1 = *(const s16x8*)&t[orow][ocg + 8];
    const int row   = c0 + orow;            // l (or f) index
    const int rtile = row >> 4, rr = row & 15;
    const int cstep = (r0 + ocg) >> 5;      // 32-col step within CDIM-like axis
    const int qb    = (ocg >> 3) & 3;       // 0 or 2
    u16* dst = out + ((size_t)(rtile * 16 + cstep) * 64 + qb * 16 + rr) * 8;
    *(s16x8*)dst = v0;                      // q = qb   half
    *(s16x8*)(dst + 128) = v1;              // q = qb+1 half
}

// ---------------- QKV GEMM (r5 config): packed-chunk loads -> QF/KF/VF --------
__global__ __launch_bounds__(256)
void qkvgemm_bf16(const u16* __restrict__ XP, const u16* __restrict__ WP,
                  u16* __restrict__ QF, u16* __restrict__ KF, u16* __restrict__ VF)
{
    const int f0 = blockIdx.x * 64;
    const int l0 = blockIdx.y * 128;
    const int b  = blockIdx.z;
    const u16* xTb = XP + (size_t)b * LDIM * CDIM;
    const int t = threadIdx.x, w = t >> 6, lane = t & 63;
    const int mn = lane & 15, q = lane >> 4;
    const bool vpart = (f0 >= 1024);

    const u16 *Abase, *Bbase;
    int mbase, nbase;
    if (!vpart) {
        mbase = f0 + (w >> 1) * 32; nbase = l0 + (w & 1) * 64;
        Abase = WP + (size_t)mbase * CDIM; Bbase = xTb + (size_t)nbase * CDIM;
    } else {
        mbase = l0 + w * 32; nbase = f0;
        Abase = xTb + (size_t)mbase * CDIM; Bbase = WP + (size_t)nbase * CDIM;
    }

    f32x4 acc[2][4] = {};
    #pragma unroll 2
    for (int c0 = 0; c0 < CDIM; c0 += 32) {
        s16x8 a[2], bf[4];
        #pragma unroll
        for (int mi = 0; mi < 2; ++mi)
            a[mi] = *(const s16x8*)(Abase + mi * 16 * CDIM + c0 * 16 + lane * 8);
        #pragma unroll
        for (int ni = 0; ni < 4; ++ni)
            bf[ni] = *(const s16x8*)(Bbase + ni * 16 * CDIM + c0 * 16 + lane * 8);
        #pragma unroll
        for (int mi = 0; mi < 2; ++mi)
            #pragma unroll
            for (int ni = 0; ni < 4; ++ni)
                acc[mi][ni] = __builtin_amdgcn_mfma_f32_16x16x32_bf16(a[mi], bf[ni], acc[mi][ni], 0, 0, 0);
    }

    if (!vpart) {
        const int part = f0 >> 9;
        const float sc2 = (part == 0) ? 0.18033688f : 1.0f;  // 0.125*log2(e)
        u16* Tout = (part == 0) ? QF : KF;
        #pragma unroll
        for (int mi = 0; mi < 2; ++mi) {
            const int fg0 = mbase + mi * 16;
            const int h = (fg0 >> 6) & 7;
            const int d0 = (fg0 & 63) + q * 4;          // 4-aligned d base
            const int kd = d0 >> 5, qq = (d0 >> 3) & 3, e0 = d0 & 7;
            u16* T = Tout + (size_t)(b * 8 + h) * LDIM * 64;
            #pragma unroll
            for (int ni = 0; ni < 4; ++ni) {
                const int lg = nbase + ni * 16 + mn;     // L index
                size_t addr;
                if (part == 0) {                         // QF[t16][kd][lane][8]
                    const int t16 = lg >> 4, mnq = lg & 15;
                    addr = (size_t)((t16 * 2 + kd) * 512 + (qq * 16 + mnq) * 8 + e0);
                } else {                                 // KF[j64][jt][kd][lane][8], kperm absorbed
                    const int j64 = lg >> 6, r6 = lg & 63;
                    const int jt  = ((r6 >> 2) & 1) * 2 + (r6 >> 5);
                    const int mnk = ((r6 >> 3) & 3) * 4 + (r6 & 3);
                    addr = (size_t)(((j64 * 4 + jt) * 2 + kd) * 512 + (qq * 16 + mnk) * 8 + e0);
                }
                u16x4 pk;
                #pragma unroll
                for (int r = 0; r < 4; ++r) pk[r] = f2b(acc[mi][ni][r] * sc2);
                *(u16x4*)(T + addr) = pk;
            }
        }
    } else {
        #pragma unroll
        for (int ni = 0; ni < 4; ++ni) {
            const int fg = nbase + ni * 16 + mn;
            const int h = (fg >> 6) & 7;
            const int d = fg & 63;
            const int dt = d >> 4, mnv = d & 15;
            u16* Vb = VF + (size_t)(b * 8 + h) * LDIM * 64;
            #pragma unroll
            for (int mi = 0; mi < 2; ++mi) {
                const int lg0 = mbase + mi * 16 + q * 4;    // 4-aligned j base
                const int j64 = lg0 >> 6, j6 = lg0 & 63;
                const int kj = j6 >> 5, qq = (j6 >> 3) & 3, e0 = j6 & 7;
                const size_t addr = (size_t)(((j64 * 2 + kj) * 4 + dt) * 512 + (qq * 16 + mnv) * 8 + e0);
                u16x4 pk;
                #pragma unroll
                for (int r = 0; r < 4; ++r) pk[r] = f2b(acc[mi][ni][r]);
                *(u16x4*)(Vb + addr) = pk;
            }
        }
    }
}

// ---------------- Flash attention: 64 i-rows, 4-wave j-split, SW-pipelined ------
// grid (x=bh 32, y=32), 256 threads (4 waves). Wave wv owns j in [wv*512,(wv+1)*512).
// Body jj: QK(jj+1) -> reload kc=K(jj+2) -> { exp/pack(jj+1) INTERLEAVED with
// PV(jj) } -> reload vc=V(jj+1) -> ap<-apn. exp hides under the PV MFMA pipe.
__global__ __launch_bounds__(256)
void attn_k(const u16* __restrict__ QF, const u16* __restrict__ KF,
            const u16* __restrict__ VF, u16* __restrict__ aoP)
{
    const int bh = blockIdx.x;
    const int b = bh >> 3, h = bh & 7;
    const u16* Qh = QF + (size_t)bh * LDIM * 64;
    const u16* Kh = KF + (size_t)bh * LDIM * 64;
    const u16* Vh = VF + (size_t)bh * LDIM * 64;

    __shared__ __align__(16) float o_sh[3][64][68];   // waves 1..3 partials (+4 pad)
    __shared__ float lp_sh[3][64];

    const int tid = threadIdx.x;
    const int wv = tid >> 6;
    const int lane = tid & 63;
    const int mn = lane & 15, q = lane >> 4;
    const int ib64 = blockIdx.y;         // 64-row i-block
    const int TH = 8;                    // j-tiles per wave (of 32 total)
    const int tbase = wv * TH;

    s16x8 aq[4][2];
    #pragma unroll
    for (int ibt = 0; ibt < 4; ++ibt) {
        const int t16 = ib64 * 4 + ibt;
        #pragma unroll
        for (int kd = 0; kd < 2; ++kd)
            aq[ibt][kd] = *(const s16x8*)(Qh + (size_t)((t16 * 2 + kd) * 512) + lane * 8);
    }

    f32x4 o_acc[4][4] = {};
    float lp[4] = {0.f, 0.f, 0.f, 0.f};

    s16x8 kc[2][4], vc[2][4], ap[2][4];

    // ---- prologue: tile 0 ----
    {
        const u16* Kt = Kh + (size_t)tbase * 4096;
        #pragma unroll
        for (int kd = 0; kd < 2; ++kd)
            #pragma unroll
            for (int jt = 0; jt < 4; ++jt)
                kc[kd][jt] = *(const s16x8*)(Kt + ((jt * 2 + kd) << 9) + (lane << 3));

        f32x4 s[4][4] = {};
        #pragma unroll
        for (int kd = 0; kd < 2; ++kd)
            #pragma unroll
            for (int jt = 0; jt < 4; ++jt)
                #pragma unroll
                for (int ibt = 0; ibt < 4; ++ibt)
                    s[ibt][jt] = __builtin_amdgcn_mfma_f32_16x16x32_bf16(kc[kd][jt], aq[ibt][kd], s[ibt][jt], 0, 0, 0);

        // reload kc = K(1) (after QK consumed it); load vc = V(0)
        const u16* Ktn = Kh + (size_t)(tbase + 1) * 4096;
        #pragma unroll
        for (int kd = 0; kd < 2; ++kd)
            #pragma unroll
            for (int jt = 0; jt < 4; ++jt)
                kc[kd][jt] = *(const s16x8*)(Ktn + ((jt * 2 + kd) << 9) + (lane << 3));
        const u16* Vt = Vh + (size_t)tbase * 4096;
        #pragma unroll
        for (int kj = 0; kj < 2; ++kj)
            #pragma unroll
            for (int dt = 0; dt < 4; ++dt)
                vc[kj][dt] = *(const s16x8*)(Vt + ((kj * 4 + dt) << 9) + (lane << 3));

        // exp/pack tile 0 -> ap
        #pragma unroll
        for (int kj = 0; kj < 2; ++kj)
            #pragma unroll
            for (int ibt = 0; ibt < 4; ++ibt) {
                float pa0 = __builtin_amdgcn_exp2f(s[ibt][kj][0]);
                float pa1 = __builtin_amdgcn_exp2f(s[ibt][kj][1]);
                float pa2 = __builtin_amdgcn_exp2f(s[ibt][kj][2]);
                float pa3 = __builtin_amdgcn_exp2f(s[ibt][kj][3]);
                float pb0 = __builtin_amdgcn_exp2f(s[ibt][kj + 2][0]);
                float pb1 = __builtin_amdgcn_exp2f(s[ibt][kj + 2][1]);
                float pb2 = __builtin_amdgcn_exp2f(s[ibt][kj + 2][2]);
                float pb3 = __builtin_amdgcn_exp2f(s[ibt][kj + 2][3]);
                lp[ibt] += ((pa0 + pa1) + (pa2 + pa3)) + ((pb0 + pb1) + (pb2 + pb3));
                union { s16x8 v; u32 w[4]; } u;
                u.w[0] = pk2(pa0, pa1);
                u.w[1] = pk2(pa2, pa3);
                u.w[2] = pk2(pb0, pb1);
                u.w[3] = pk2(pb2, pb3);
                ap[kj][ibt] = u.v;
            }
    }

    // ---- pipelined main loop: body jj does QK(jj+1), exp(jj+1) || PV(jj) ----
    for (int jj = 0; jj < TH - 1; ++jj) {
        // QK for tile jj+1 (kc holds K(jj+1))
        f32x4 s[4][4] = {};
        #pragma unroll
        for (int kd = 0; kd < 2; ++kd)
            #pragma unroll
            for (int jt = 0; jt < 4; ++jt)
                #pragma unroll
                for (int ibt = 0; ibt < 4; ++ibt)
                    s[ibt][jt] = __builtin_amdgcn_mfma_f32_16x16x32_bf16(kc[kd][jt], aq[ibt][kd], s[ibt][jt], 0, 0, 0);

        // reload kc = K(jj+2) (wrap; cover = exp/PV phase)
        {
            const u16* Ktn = Kh + (size_t)(tbase + ((jj + 2) & (TH - 1))) * 4096;
            #pragma unroll
            for (int kd = 0; kd < 2; ++kd)
                #pragma unroll
                for (int jt = 0; jt < 4; ++jt)
                    kc[kd][jt] = *(const s16x8*)(Ktn + ((jt * 2 + kd) << 9) + (lane << 3));
        }

        // exp/pack tile jj+1 (VALU) interleaved with PV tile jj (MFMA) — independent
        s16x8 apn[2][4];
        #pragma unroll
        for (int kj = 0; kj < 2; ++kj)
            #pragma unroll
            for (int ibt = 0; ibt < 4; ++ibt) {
                float pa0 = __builtin_amdgcn_exp2f(s[ibt][kj][0]);
                float pa1 = __builtin_amdgcn_exp2f(s[ibt][kj][1]);
                float pa2 = __builtin_amdgcn_exp2f(s[ibt][kj][2]);
                float pa3 = __builtin_amdgcn_exp2f(s[ibt][kj][3]);
                float pb0 = __builtin_amdgcn_exp2f(s[ibt][kj + 2][0]);
                float pb1 = __builtin_amdgcn_exp2f(s[ibt][kj + 2][1]);
                float pb2 = __builtin_amdgcn_exp2f(s[ibt][kj + 2][2]);
                float pb3 = __builtin_amdgcn_exp2f(s[ibt][kj + 2][3]);
                lp[ibt] += ((pa0 + pa1) + (pa2 + pa3)) + ((pb0 + pb1) + (pb2 + pb3));
                union { s16x8 v; u32 w[4]; } u;
                u.w[0] = pk2(pa0, pa1);
                u.w[1] = pk2(pa2, pa3);
                u.w[2] = pk2(pb0, pb1);
                u.w[3] = pk2(pb2, pb3);
                apn[kj][ibt] = u.v;
                // PV slice for tile jj (old ap) — hides the exp above
                #pragma unroll
                for (int dt = 0; dt < 4; ++dt)
                    o_acc[ibt][dt] = __builtin_amdgcn_mfma_f32_16x16x32_bf16(vc[kj][dt], ap[kj][ibt], o_acc[ibt][dt], 0, 0, 0);
            }

        // reload vc = V(jj+1) (after PV consumed it; cover = next QK+exp)
        {
            const u16* Vtn = Vh + (size_t)(tbase + jj + 1) * 4096;
            #pragma unroll
            for (int kj = 0; kj < 2; ++kj)
                #pragma unroll
                for (int dt = 0; dt < 4; ++dt)
                    vc[kj][dt] = *(const s16x8*)(Vtn + ((kj * 4 + dt) << 9) + (lane << 3));
        }

        // rotate packed P
        #pragma unroll
        for (int kj = 0; kj < 2; ++kj)
            #pragma unroll
            for (int ibt = 0; ibt < 4; ++ibt)
                ap[kj][ibt] = apn[kj][ibt];
    }

    // ---- epilogue: PV for last tile ----
    #pragma unroll
    for (int kj = 0; kj < 2; ++kj)
        #pragma unroll
        for (int ibt = 0; ibt < 4; ++ibt)
            #pragma unroll
            for (int dt = 0; dt < 4; ++dt)
                o_acc[ibt][dt] = __builtin_amdgcn_mfma_f32_16x16x32_bf16(vc[kj][dt], ap[kj][ibt], o_acc[ibt][dt], 0, 0, 0);

    #pragma unroll
    for (int ibt = 0; ibt < 4; ++ibt) {
        lp[ibt] += __shfl_xor(lp[ibt], 16);
        lp[ibt] += __shfl_xor(lp[ibt], 32);
    }

    // combine the four waves' j-partials: plain addition (sum-normalized softmax)
    if (wv != 0) {
        #pragma unroll
        for (int ibt = 0; ibt < 4; ++ibt) {
            #pragma unroll
            for (int dt = 0; dt < 4; ++dt)
                *(f32x4*)&o_sh[wv - 1][ibt * 16 + mn][dt * 16 + q * 4] = o_acc[ibt][dt];
            if (q == 0) lp_sh[wv - 1][ibt * 16 + mn] = lp[ibt];
        }
    }
    __syncthreads();
    if (wv == 0) {
        u16* Ab = aoP + (size_t)b * LDIM * 512;
        #pragma unroll
        for (int ibt = 0; ibt < 4; ++ibt) {
            const int row = ibt * 16 + mn;
            const float lptot = lp[ibt] + lp_sh[0][row] + lp_sh[1][row] + lp_sh[2][row];
            const float rinv = 1.0f / lptot;
            const int ltile = ib64 * 4 + ibt;
            #pragma unroll
            for (int dt = 0; dt < 4; ++dt) {
                f32x4 o0 = *(const f32x4*)&o_sh[0][row][dt * 16 + q * 4];
                f32x4 o1 = *(const f32x4*)&o_sh[1][row][dt * 16 + q * 4];
                f32x4 o2 = *(const f32x4*)&o_sh[2][row][dt * 16 + q * 4];
                u16x4 pk;
                #pragma unroll
                for (int r = 0; r < 4; ++r)
                    pk[r] = f2b((o_acc[ibt][dt][r] + o0[r] + o1[r] + o2[r]) * rinv);
                // packed-chunk store: col = h*64 + dt*16 + q*4 + r
                const int cstep = h * 2 + (dt >> 1);
                const int lanep = ((dt & 1) * 2 + (q >> 1)) * 16 + mn;
                u16* dst = Ab + ((size_t)(ltile * 16 + cstep) * 64 + lanep) * 8 + (q & 1) * 4;
                *(u16x4*)dst = pk;
            }
        }
    }
}

// ---------------- Output GEMM (r5 config): packed-chunk loads ----------------
__global__ __launch_bounds__(256)
void outgemm_d(const u16* __restrict__ aoP, const u16* __restrict__ WOP,
               const float* __restrict__ bias, float* __restrict__ Y)
{
    const int f0 = blockIdx.x * 64;
    const int l0 = blockIdx.y * 128;
    const int b  = blockIdx.z;
    const int t = threadIdx.x, w = t >> 6, lane = t & 63;
    const int mn = lane & 15, q = lane >> 4;
    const int mbase = f0 + (w >> 1) * 32;
    const int nbase = l0 + (w & 1) * 64;
    const u16* Abase = WOP + (size_t)mbase * CDIM;
    const u16* Bbase = aoP + ((size_t)b * LDIM + nbase) * CDIM;
    float* Yb = Y + (size_t)b * CDIM * LDIM;

    f32x4 acc[2][4] = {};
    #pragma unroll 2
    for (int c0 = 0; c0 < CDIM; c0 += 32) {
        s16x8 a[2], bf[4];
        #pragma unroll
        for (int mi = 0; mi < 2; ++mi)
            a[mi] = *(const s16x8*)(Abase + mi * 16 * CDIM + c0 * 16 + lane * 8);
        #pragma unroll
        for (int ni = 0; ni < 4; ++ni)
            bf[ni] = *(const s16x8*)(Bbase + ni * 16 * CDIM + c0 * 16 + lane * 8);
        #pragma unroll
        for (int mi = 0; mi < 2; ++mi)
            #pragma unroll
            for (int ni = 0; ni < 4; ++ni)
                acc[mi][ni] = __builtin_amdgcn_mfma_f32_16x16x32_bf16(a[mi], bf[ni], acc[mi][ni], 0, 0, 0);
    }
    #pragma unroll
    for (int mi = 0; mi < 2; ++mi)
        #pragma unroll
        for (int r = 0; r < 4; ++r) {
            const int f = mbase + mi * 16 + q * 4 + r;
            const float bs = bias[f];
            #pragma unroll
            for (int ni = 0; ni < 4; ++ni)
                Yb[(size_t)f * LDIM + nbase + ni * 16 + mn] = acc[mi][ni][r] + bs;
        }
}

extern "C" void kernel_launch(void* const* d_in, const int* in_sizes, int n_in,
                              void* d_out, int out_size, void* d_ws, size_t ws_size,
                              hipStream_t stream) {
    const float *x = nullptr, *w_qkv = nullptr, *w_out = nullptr, *b_out = nullptr;
    for (int i = 0; i < n_in; ++i) {
        switch (in_sizes[i]) {
            case 4 * 512 * 2048: x     = (const float*)d_in[i]; break;
            case 512 * 1536:     w_qkv = (const float*)d_in[i]; break;
            case 512 * 512:      w_out = (const float*)d_in[i]; break;
            case 512:            b_out = (const float*)d_in[i]; break;
        }
    }
    float* out = (float*)d_out;                 // [4][512][2048] f32

    const size_t SLAB = (size_t)BATCH * LDIM * 512;      // 4194304 elems
    u16* WOP = (u16*)d_ws;                               // [512 rows][512] packed
    u16* XP  = WOP + (size_t)512 * 512;                  // [4][2048 rows][512] packed
    u16* WP  = XP + SLAB;                                // [1536 rows][512] packed
    u16* QF  = WP + (size_t)1536 * 512;                  // [32][2048*64] attn-packed
    u16* KF  = QF + SLAB;                                // [32][2048*64] attn-packed
    u16* VF  = KF + SLAB;                                // [32][2048*64] attn-packed
    u16* aoP = VF + SLAB;                                // [4][2048 rows][512] packed

    transpA_k<<<dim3(8, 160), 256, 0, stream>>>(x, w_qkv, w_out, XP, WP, WOP);
    qkvgemm_bf16<<<dim3(24, 16, BATCH), 256, 0, stream>>>(XP, WP, QF, KF, VF);
    attn_k<<<dim3(32, 32), 256, 0, stream>>>(QF, KF, VF, aoP);
    outgemm_d<<<dim3(8, 16, BATCH), 256, 0, stream>>>(aoP, WOP, b_out, out);
}